// Round 1
// baseline (162.286 us; speedup 1.0000x reference)
//
#include <hip/hip_runtime.h>
#include <hip/hip_bf16.h>

#define N_NODES 50000
#define NLAT 10
#define MU 32
#define BATCH 8

// ---------------- Kernel 1: encoded[b,i] = dot(x[b,:], enc_w[i,:]) + enc_b[i]
// 80 blocks (one per (b,i)), 256 threads, double accumulation for accuracy.
__global__ __launch_bounds__(256) void encode_kernel(
    const float* __restrict__ x, const float* __restrict__ enc_w,
    const float* __restrict__ enc_b, float* __restrict__ enc_out) {
    const int b = blockIdx.x / NLAT;
    const int i = blockIdx.x % NLAT;
    const float4* xr = (const float4*)(x + (size_t)b * N_NODES);
    const float4* wr = (const float4*)(enc_w + (size_t)i * N_NODES);
    double part = 0.0;
    for (int q = threadIdx.x; q < N_NODES / 4; q += 256) {
        float4 xv = xr[q];
        float4 wv = wr[q];
        part += (double)xv.x * (double)wv.x;
        part += (double)xv.y * (double)wv.y;
        part += (double)xv.z * (double)wv.z;
        part += (double)xv.w * (double)wv.w;
    }
    __shared__ double red[256];
    red[threadIdx.x] = part;
    __syncthreads();
    for (int s = 128; s > 0; s >>= 1) {
        if (threadIdx.x < s) red[threadIdx.x] += red[threadIdx.x + s];
        __syncthreads();
    }
    if (threadIdx.x == 0)
        enc_out[blockIdx.x] = (float)red[0] + enc_b[i];
}

// ---------------- Kernel 2: main fused kernel, one thread per node p.
// out[b,p] = sum_i enc[b,i] * ( sum_m g[i,m]*win(b,i,m) / sum_m win(b,i,m) )
// where g[i,m] = decoder[i, nbr[p,m]],
//       win = relu(1 - m^2 / (sigmoid(sum_k enc[b,k]*bw[i,k,p]) * MU)^2)
__global__ __launch_bounds__(256) void nrbs_main_kernel(
    const float* __restrict__ decoder,
    const float* __restrict__ bw,       // [n, n, N] : (i*NLAT+k)*N + p
    const int*   __restrict__ nbr,      // [N, MU]
    const float* __restrict__ enc,      // [B, n]
    float*       __restrict__ out) {    // [B, N]
    __shared__ float s_enc[BATCH * NLAT];
    const int tid = threadIdx.x;
    if (tid < BATCH * NLAT) s_enc[tid] = enc[tid];
    __syncthreads();

    const int p = blockIdx.x * 256 + tid;
    if (p >= N_NODES) return;

    // neighbour row: contiguous 128B, 128B-aligned -> int4 loads
    int nb[MU];
    const int4* nb4 = (const int4*)(nbr + (size_t)p * MU);
#pragma unroll
    for (int q = 0; q < MU / 4; ++q) {
        int4 v = nb4[q];
        nb[4 * q + 0] = v.x; nb[4 * q + 1] = v.y;
        nb[4 * q + 2] = v.z; nb[4 * q + 3] = v.w;
    }

    float accOut[BATCH];
#pragma unroll
    for (int b = 0; b < BATCH; ++b) accOut[b] = 0.0f;

#pragma unroll 1   // keep i-loop rolled: controls VGPR pressure
    for (int i = 0; i < NLAT; ++i) {
        // gather decoder row i at the 32 neighbours (b-independent!)
        float g[MU];
        const float* drow = decoder + (size_t)i * N_NODES;
#pragma unroll
        for (int m = 0; m < MU; ++m) g[m] = drow[nb[m]];

        // bandwidth coeffs for this (i, p): coalesced across threads
        float bwv[NLAT];
#pragma unroll
        for (int k = 0; k < NLAT; ++k)
            bwv[k] = bw[((size_t)(i * NLAT + k)) * N_NODES + p];

#pragma unroll
        for (int b = 0; b < BATCH; ++b) {
            float z = 0.0f;
#pragma unroll
            for (int k = 0; k < NLAT; ++k)
                z = fmaf(s_enc[b * NLAT + k], bwv[k], z);
            const float wv = 1.0f / (1.0f + __expf(-z));   // sigmoid
            const float t = wv * (float)MU;
            const float inv = 1.0f / (t * t);
            float ssum = 0.0f, asum = 0.0f;
#pragma unroll
            for (int m = 0; m < MU; ++m) {
                const float win = fmaxf(0.0f, fmaf(-(float)(m * m), inv, 1.0f));
                ssum += win;
                asum = fmaf(g[m], win, asum);
            }
            accOut[b] = fmaf(s_enc[b * NLAT + i], asum / ssum, accOut[b]);
        }
    }

#pragma unroll
    for (int b = 0; b < BATCH; ++b)
        out[(size_t)b * N_NODES + p] = accOut[b];
}

extern "C" void kernel_launch(void* const* d_in, const int* in_sizes, int n_in,
                              void* d_out, int out_size, void* d_ws, size_t ws_size,
                              hipStream_t stream) {
    const float* x       = (const float*)d_in[0];   // [B, N]
    const float* enc_w   = (const float*)d_in[1];   // [n, N]
    const float* enc_b   = (const float*)d_in[2];   // [n]
    const float* decoder = (const float*)d_in[3];   // [n, N]
    const float* bwl     = (const float*)d_in[4];   // [n, n, N]
    const int*   nbr     = (const int*)d_in[5];     // [N, MU]
    float* out = (float*)d_out;                     // [B, N]
    float* enc = (float*)d_ws;                      // 80 floats scratch

    encode_kernel<<<BATCH * NLAT, 256, 0, stream>>>(x, enc_w, enc_b, enc);

    const int blocks = (N_NODES + 255) / 256;
    nrbs_main_kernel<<<blocks, 256, 0, stream>>>(decoder, bwl, nbr, enc, out);
}

// Round 2
// 158.360 us; speedup vs baseline: 1.0248x; 1.0248x over previous
//
#include <hip/hip_runtime.h>
#include <hip/hip_bf16.h>

#define N_NODES 50000
#define NLAT 10
#define MU 32
#define BATCH 8
#define CHUNK 2000          // encode split-K chunk (floats), 25 chunks per row
#define NCHUNK 25

// ---------------- Encode stage A: partial[b,i,c] = dot(x[b, c-chunk], enc_w[i, c-chunk])
// grid = 80*25 = 2000 blocks -> 8000 waves, latency well hidden.
__global__ __launch_bounds__(256) void encode_stage_a(
    const float* __restrict__ x, const float* __restrict__ enc_w,
    float* __restrict__ partial) {
    const int blk = blockIdx.x;          // (b*10+i)*25 + c
    const int c  = blk % NCHUNK;
    const int bi = blk / NCHUNK;
    const int b = bi / NLAT, i = bi % NLAT;
    const float4* xr = (const float4*)(x + (size_t)b * N_NODES + c * CHUNK);
    const float4* wr = (const float4*)(enc_w + (size_t)i * N_NODES + c * CHUNK);
    float part = 0.0f;
    for (int q = threadIdx.x; q < CHUNK / 4; q += 256) {
        float4 xv = xr[q], wv = wr[q];
        part += xv.x * wv.x + xv.y * wv.y + xv.z * wv.z + xv.w * wv.w;
    }
    // wave reduce (64-wide), then cross-wave via LDS
    for (int off = 32; off; off >>= 1) part += __shfl_down(part, off, 64);
    __shared__ float s[4];
    if ((threadIdx.x & 63) == 0) s[threadIdx.x >> 6] = part;
    __syncthreads();
    if (threadIdx.x == 0) partial[blk] = (s[0] + s[1]) + (s[2] + s[3]);
}

// ---------------- Encode stage B: enc[b,i] = sum_c partial[b,i,c] + enc_b[i]
__global__ __launch_bounds__(128) void encode_stage_b(
    const float* __restrict__ partial, const float* __restrict__ enc_b,
    float* __restrict__ enc) {
    const int t = threadIdx.x;
    if (t < BATCH * NLAT) {
        float s = 0.0f;
        #pragma unroll
        for (int c = 0; c < NCHUNK; ++c) s += partial[t * NCHUNK + c];
        enc[t] = s + enc_b[t % NLAT];
    }
}

// ---------------- Main kernel: thread = (node_local, i). Block = 32 nodes x 10 i = 320 thr.
// Each thread computes, for its (p, i), the contribution over all 8 batches:
//   c[b] = enc[b,i] * (sum_m g[m]*win[b,m]) / (sum_m win[b,m])
// then LDS-reduce over i and write out[b,p] coalesced.
__global__ __launch_bounds__(320) void nrbs_main_kernel(
    const float* __restrict__ decoder,   // [n, N]
    const float* __restrict__ bw,        // [n, n, N]
    const int*   __restrict__ nbr,       // [N, MU]
    const float* __restrict__ enc,       // [B, n]
    float*       __restrict__ out) {     // [B, N]
    __shared__ float s_enc[BATCH * NLAT];
    __shared__ float s_part[32 * BATCH * NLAT];   // [nl][b*10+i], 10 KB
    const int tid = threadIdx.x;
    if (tid < BATCH * NLAT) s_enc[tid] = enc[tid];
    __syncthreads();

    const int node0 = blockIdx.x * 32;
    const int i  = tid >> 5;      // 0..9
    const int nl = tid & 31;      // 0..31
    const int p  = node0 + nl;

    if (p < N_NODES) {
        // z[b] = sum_k enc[b,k] * bw[i,k,p]   (bw loads coalesced over nl)
        float z[BATCH];
        #pragma unroll
        for (int b = 0; b < BATCH; ++b) z[b] = 0.0f;
        #pragma unroll
        for (int k = 0; k < NLAT; ++k) {
            const float bwv = bw[((size_t)(i * NLAT + k)) * N_NODES + p];
            #pragma unroll
            for (int b = 0; b < BATCH; ++b)
                z[b] = fmaf(s_enc[b * NLAT + k], bwv, z[b]);
        }
        float inv[BATCH], ssum[BATCH], asum[BATCH];
        #pragma unroll
        for (int b = 0; b < BATCH; ++b) {
            const float w = 1.0f / (1.0f + __expf(-z[b]));   // sigmoid
            const float t = w * (float)MU;
            inv[b] = 1.0f / (t * t);
            ssum[b] = 0.0f;
            asum[b] = 0.0f;
        }
        // neighbourhood loop in chunks of 4 (one int4) to keep VGPRs low
        const float* drow = decoder + (size_t)i * N_NODES;
        const int4* nb4 = (const int4*)(nbr + (size_t)p * MU);
        #pragma unroll
        for (int q = 0; q < MU / 4; ++q) {
            const int4 v = nb4[q];
            const float g0 = drow[v.x], g1 = drow[v.y],
                        g2 = drow[v.z], g3 = drow[v.w];
            const float m0 = (float)((4 * q + 0) * (4 * q + 0));
            const float m1 = (float)((4 * q + 1) * (4 * q + 1));
            const float m2 = (float)((4 * q + 2) * (4 * q + 2));
            const float m3 = (float)((4 * q + 3) * (4 * q + 3));
            #pragma unroll
            for (int b = 0; b < BATCH; ++b) {
                const float w0 = fmaxf(0.0f, fmaf(-m0, inv[b], 1.0f));
                const float w1 = fmaxf(0.0f, fmaf(-m1, inv[b], 1.0f));
                const float w2 = fmaxf(0.0f, fmaf(-m2, inv[b], 1.0f));
                const float w3 = fmaxf(0.0f, fmaf(-m3, inv[b], 1.0f));
                ssum[b] += (w0 + w1) + (w2 + w3);
                asum[b] = fmaf(g0, w0, fmaf(g1, w1,
                          fmaf(g2, w2, fmaf(g3, w3, asum[b]))));
            }
        }
        #pragma unroll
        for (int b = 0; b < BATCH; ++b)
            s_part[nl * (BATCH * NLAT) + b * NLAT + i] =
                s_enc[b * NLAT + i] * asum[b] / ssum[b];
    }
    __syncthreads();

    // reduce over i; thread t: b = t>>5, node = t&31 -> coalesced stores
    if (tid < 256) {
        const int b = tid >> 5, nl2 = tid & 31, p2 = node0 + nl2;
        if (p2 < N_NODES) {
            float s = 0.0f;
            #pragma unroll
            for (int ii = 0; ii < NLAT; ++ii)
                s += s_part[nl2 * (BATCH * NLAT) + b * NLAT + ii];
            out[(size_t)b * N_NODES + p2] = s;
        }
    }
}

extern "C" void kernel_launch(void* const* d_in, const int* in_sizes, int n_in,
                              void* d_out, int out_size, void* d_ws, size_t ws_size,
                              hipStream_t stream) {
    const float* x       = (const float*)d_in[0];   // [B, N]
    const float* enc_w   = (const float*)d_in[1];   // [n, N]
    const float* enc_b   = (const float*)d_in[2];   // [n]
    const float* decoder = (const float*)d_in[3];   // [n, N]
    const float* bwl     = (const float*)d_in[4];   // [n, n, N]
    const int*   nbr     = (const int*)d_in[5];     // [N, MU]
    float* out = (float*)d_out;                     // [B, N]

    float* enc     = (float*)d_ws;                  // 80 floats
    float* partial = (float*)d_ws + 128;            // 2000 floats, 16B aligned

    encode_stage_a<<<BATCH * NLAT * NCHUNK, 256, 0, stream>>>(x, enc_w, partial);
    encode_stage_b<<<1, 128, 0, stream>>>(partial, enc_b, enc);

    const int blocks = (N_NODES + 31) / 32;         // 1563
    nrbs_main_kernel<<<blocks, 320, 0, stream>>>(decoder, bwl, nbr, enc, out);
}

// Round 3
// 111.691 us; speedup vs baseline: 1.4530x; 1.4178x over previous
//
#include <hip/hip_runtime.h>
#include <hip/hip_bf16.h>

#define N_NODES 50000
#define NLAT 10
#define MU 32
#define BATCH 8
#define CHUNK 2000          // encode split-K chunk (floats), 25 chunks per row
#define NCHUNK 25
#define DT_STRIDE 16        // padded floats per node in transposed decoder (64B = 1 line)

// ---------------- Encode stage A: partial[b,i,c] = dot chunks
__global__ __launch_bounds__(256) void encode_stage_a(
    const float* __restrict__ x, const float* __restrict__ enc_w,
    float* __restrict__ partial) {
    const int blk = blockIdx.x;          // (b*10+i)*25 + c
    const int c  = blk % NCHUNK;
    const int bi = blk / NCHUNK;
    const int b = bi / NLAT, i = bi % NLAT;
    const float4* xr = (const float4*)(x + (size_t)b * N_NODES + c * CHUNK);
    const float4* wr = (const float4*)(enc_w + (size_t)i * N_NODES + c * CHUNK);
    float part = 0.0f;
    for (int q = threadIdx.x; q < CHUNK / 4; q += 256) {
        float4 xv = xr[q], wv = wr[q];
        part += xv.x * wv.x + xv.y * wv.y + xv.z * wv.z + xv.w * wv.w;
    }
    for (int off = 32; off; off >>= 1) part += __shfl_down(part, off, 64);
    __shared__ float s[4];
    if ((threadIdx.x & 63) == 0) s[threadIdx.x >> 6] = part;
    __syncthreads();
    if (threadIdx.x == 0) partial[blk] = (s[0] + s[1]) + (s[2] + s[3]);
}

// ---------------- Encode stage B: enc[b,i] = sum_c partial + bias
__global__ __launch_bounds__(128) void encode_stage_b(
    const float* __restrict__ partial, const float* __restrict__ enc_b,
    float* __restrict__ enc) {
    const int t = threadIdx.x;
    if (t < BATCH * NLAT) {
        float s = 0.0f;
        #pragma unroll
        for (int c = 0; c < NCHUNK; ++c) s += partial[t * NCHUNK + c];
        enc[t] = s + enc_b[t % NLAT];
    }
}

// ---------------- Transpose decoder [n,N] -> dec_t [N,16] (node-major, line-aligned)
__global__ __launch_bounds__(256) void transpose_dec(
    const float* __restrict__ dec, float* __restrict__ dec_t) {
    const int p = blockIdx.x * 256 + threadIdx.x;
    if (p >= N_NODES) return;
    float v[DT_STRIDE];
    #pragma unroll
    for (int i = 0; i < NLAT; ++i) v[i] = dec[(size_t)i * N_NODES + p];
    #pragma unroll
    for (int i = NLAT; i < DT_STRIDE; ++i) v[i] = 0.0f;
    float4* dst = (float4*)(dec_t + (size_t)p * DT_STRIDE);
    #pragma unroll
    for (int q = 0; q < 4; ++q)
        dst[q] = make_float4(v[4*q], v[4*q+1], v[4*q+2], v[4*q+3]);
}

// ---------------- Main kernel: thread = (node, batch). Block = 32 nodes x 8 b.
// Wave = 8 nodes x 8 batches -> the 8 batch-lanes of a node issue IDENTICAL
// gather addresses (TA coalesces), and all 10 latent decoder values for a
// neighbour sit in ONE 64B line (dec_t). Dynamic m-cap: win=0 for m >= mcap.
template<bool TR>
__global__ __launch_bounds__(256) void nrbs_main_kernel(
    const float* __restrict__ dec,      // [n, N]   (fallback path)
    const float* __restrict__ dec_t,    // [N, 16]  (TR path)
    const float* __restrict__ bw,       // [n, n, N]
    const int*   __restrict__ nbr,      // [N, MU]
    const float* __restrict__ enc,      // [B, n]
    float*       __restrict__ out) {    // [B, N]
    __shared__ float s_enc[BATCH * NLAT];
    const int tid = threadIdx.x;
    if (tid < BATCH * NLAT) s_enc[tid] = enc[tid];
    __syncthreads();

    const int b  = tid & 7;
    const int nl = tid >> 3;                 // 0..31
    const int p  = blockIdx.x * 32 + nl;
    if (p >= N_NODES) return;

    // inv[i] = 1/(sigmoid(z_i)*MU)^2 ; track max support t for m-cap
    float inv[NLAT];
    float tmax = 0.0f;
    #pragma unroll
    for (int i = 0; i < NLAT; ++i) {
        float z = 0.0f;
        #pragma unroll
        for (int k = 0; k < NLAT; ++k)
            z = fmaf(s_enc[b * NLAT + k],
                     bw[((size_t)(i * NLAT + k)) * N_NODES + p], z);
        const float w = 1.0f / (1.0f + __expf(-z));
        const float t = w * (float)MU;
        tmax = fmaxf(tmax, t);
        inv[i] = 1.0f / (t * t);
    }
    const int mcap = min(MU, (int)tmax + 1);   // win(m)=0 for all i when m >= mcap

    float asum[NLAT], ssum[NLAT];
    #pragma unroll
    for (int i = 0; i < NLAT; ++i) { asum[i] = 0.0f; ssum[i] = 0.0f; }

    const int4* nb4 = (const int4*)(nbr + (size_t)p * MU);
    for (int q = 0; 4 * q < mcap; ++q) {       // padded chunks: extra m give win=0
        const int4 v = nb4[q];
        const int idx[4] = {v.x, v.y, v.z, v.w};
        #pragma unroll
        for (int j = 0; j < 4; ++j) {
            const int m = 4 * q + j;
            const float m2 = (float)(m * m);
            float g[NLAT];
            if (TR) {
                const float4* gp = (const float4*)(dec_t + (size_t)idx[j] * DT_STRIDE);
                const float4 g0 = gp[0], g1 = gp[1], g2 = gp[2];
                g[0]=g0.x; g[1]=g0.y; g[2]=g0.z; g[3]=g0.w;
                g[4]=g1.x; g[5]=g1.y; g[6]=g1.z; g[7]=g1.w;
                g[8]=g2.x; g[9]=g2.y;
            } else {
                #pragma unroll
                for (int i = 0; i < NLAT; ++i)
                    g[i] = dec[(size_t)i * N_NODES + idx[j]];
            }
            #pragma unroll
            for (int i = 0; i < NLAT; ++i) {
                const float win = fmaxf(0.0f, fmaf(-m2, inv[i], 1.0f));
                ssum[i] += win;
                asum[i] = fmaf(g[i], win, asum[i]);
            }
        }
    }

    float acc = 0.0f;
    #pragma unroll
    for (int i = 0; i < NLAT; ++i)
        acc = fmaf(s_enc[b * NLAT + i], asum[i] / ssum[i], acc);
    out[(size_t)b * N_NODES + p] = acc;
}

extern "C" void kernel_launch(void* const* d_in, const int* in_sizes, int n_in,
                              void* d_out, int out_size, void* d_ws, size_t ws_size,
                              hipStream_t stream) {
    const float* x       = (const float*)d_in[0];   // [B, N]
    const float* enc_w   = (const float*)d_in[1];   // [n, N]
    const float* enc_b   = (const float*)d_in[2];   // [n]
    const float* decoder = (const float*)d_in[3];   // [n, N]
    const float* bwl     = (const float*)d_in[4];   // [n, n, N]
    const int*   nbr     = (const int*)d_in[5];     // [N, MU]
    float* out = (float*)d_out;                     // [B, N]

    float* enc     = (float*)d_ws;                                   // 80 floats
    float* partial = (float*)((char*)d_ws + 1024);                   // 2000 floats
    float* dec_t   = (float*)((char*)d_ws + 65536);                  // 3.2 MB
    const size_t need = 65536 + (size_t)N_NODES * DT_STRIDE * 4;

    encode_stage_a<<<BATCH * NLAT * NCHUNK, 256, 0, stream>>>(x, enc_w, partial);
    encode_stage_b<<<1, 128, 0, stream>>>(partial, enc_b, enc);

    const int blocks = (N_NODES + 31) / 32;   // 1563
    if (ws_size >= need) {
        transpose_dec<<<(N_NODES + 255) / 256, 256, 0, stream>>>(decoder, dec_t);
        nrbs_main_kernel<true><<<blocks, 256, 0, stream>>>(
            decoder, dec_t, bwl, nbr, enc, out);
    } else {
        nrbs_main_kernel<false><<<blocks, 256, 0, stream>>>(
            decoder, dec_t, bwl, nbr, enc, out);
    }
}